// Round 13
// baseline (73.813 us; speedup 1.0000x reference)
//
#include <hip/hip_runtime.h>
#include <hip/hip_bf16.h>

#define NB   16384
#define NG   8
#define ND   2048
#define NR   6
#define NKC  48
#define NOUT 54
#define NT16 (NB / 16 + NG)       // 1032 tiles of 16 samples
#define LROW 136                  // tier-3 fallback gemm
#define BM   32
#define KC   128
#define NCH  (ND / KC)
#define MAXT (NB / BM + NG)

typedef __attribute__((ext_vector_type(8))) short short8_t;
typedef __attribute__((ext_vector_type(4))) float f32x4;

__device__ __forceinline__ unsigned short f2bf(float x) {
    union { float f; unsigned u; } v; v.f = x;
    unsigned r = v.u + 0x7FFFu + ((v.u >> 16) & 1u);   // RNE
    return (unsigned short)(r >> 16);
}

__device__ __forceinline__ short8_t cvt8(float4 a, float4 b) {
    short8_t s;
    s[0] = (short)f2bf(a.x); s[1] = (short)f2bf(a.y);
    s[2] = (short)f2bf(a.z); s[3] = (short)f2bf(a.w);
    s[4] = (short)f2bf(b.x); s[5] = (short)f2bf(b.y);
    s[6] = (short)f2bf(b.z); s[7] = (short)f2bf(b.w);
    return s;
}

__device__ __forceinline__ void gl_lds16(const void* g, void* s) {
    __builtin_amdgcn_global_load_lds(
        (const __attribute__((address_space(1))) void*)g,
        (__attribute__((address_space(3))) void*)s,
        16, 0, 0);
}

#define WAITV(N) do { asm volatile("s_waitcnt vmcnt(" #N ")" ::: "memory"); \
                      __builtin_amdgcn_sched_barrier(0); } while (0)
#define BAR() do { __builtin_amdgcn_s_barrier(); \
                   __builtin_amdgcn_sched_barrier(0); } while (0)

// ---- histogram (tier-3) ----
__global__ void hist_kernel(const int* __restrict__ roi, int* __restrict__ counts) {
    int i = blockIdx.x * 256 + threadIdx.x;
    int g = roi[i];
    int lane = threadIdx.x & 63;
    #pragma unroll
    for (int gg = 0; gg < NG; ++gg) {
        unsigned long long m = __ballot(g == gg);
        if (m && lane == (int)(__ffsll((unsigned long long)m) - 1))
            atomicAdd(&counts[gg], (int)__popcll(m));
    }
}

// ---- scatter into packed regions (tier-3) ----
__global__ void scatter_kernel(const int* __restrict__ roi, const int* __restrict__ counts,
                               int* __restrict__ ranks, int* __restrict__ perm) {
    int off[NG];
    int acc = 0;
    #pragma unroll
    for (int gg = 0; gg < NG; ++gg) { off[gg] = acc; acc += counts[gg]; }
    int i = blockIdx.x * 256 + threadIdx.x;
    int g = roi[i];
    int lane = threadIdx.x & 63;
    #pragma unroll
    for (int gg = 0; gg < NG; ++gg) {
        unsigned long long m = __ballot(g == gg);
        if (!m) continue;
        int leader = (int)(__ffsll((unsigned long long)m) - 1);
        int base = 0;
        if (lane == leader) base = atomicAdd(&ranks[gg], (int)__popcll(m));
        base = __shfl(base, leader);
        if (g == gg) {
            int rank = (int)__popcll(m & ((1ull << lane) - 1ull));
            perm[off[gg] + base + rank] = i;
        }
    }
}

// ---- merged pre-pass: blocks 0..63 scatter roi; 64..575 build the W blob ----
// blob unit u (16B): l=u&63, q=(u>>6)&7, c=(u>>9)&31, g=u>>14; n=q>>1, ks=q&1
// content = W[g][n*16 + (l&15)][c*64 + ks*32 + (l>>4)*8 .. +8)
__global__ void prep_kernel(const int* __restrict__ roi, int* __restrict__ cnt,
                            int* __restrict__ perm,
                            const float* __restrict__ Wreg, const float* __restrict__ Wcls,
                            short* __restrict__ Wbf) {
    if (blockIdx.x < 64) {
        int i = blockIdx.x * 256 + threadIdx.x;
        int g = roi[i];
        int lane = threadIdx.x & 63;
        #pragma unroll
        for (int gg = 0; gg < NG; ++gg) {
            unsigned long long m = __ballot(g == gg);
            if (!m) continue;
            int leader = (int)(__ffsll((unsigned long long)m) - 1);
            int base = 0;
            if (lane == leader) base = atomicAdd(&cnt[gg], (int)__popcll(m));
            base = __shfl(base, leader);
            if (g == gg) {
                int rank = (int)__popcll(m & ((1ull << lane) - 1ull));
                perm[gg * NB + base + rank] = i;
            }
        }
    } else {
        int u = (blockIdx.x - 64) * 256 + threadIdx.x;   // 131072 units
        int l = u & 63;
        int q = (u >> 6) & 7;
        int c = (u >> 9) & 31;
        int g = u >> 14;
        int n = q >> 1, ks = q & 1;
        int row = n * 16 + (l & 15);
        int k   = c * 64 + ks * 32 + (l >> 4) * 8;
        short8_t v = {0, 0, 0, 0, 0, 0, 0, 0};
        if (row < NOUT) {
            const float* s = (row < NR) ? Wreg + (size_t)(g * NR + row) * ND + k
                                        : Wcls + (size_t)(g * NKC + row - NR) * ND + k;
            float4 a = *(const float4*)s;
            float4 b = *(const float4*)(s + 4);
            v = cvt8(a, b);
        }
        *(short8_t*)(Wbf + (size_t)u * 8) = v;
    }
}

// ---- primary: BM=16 grouped GEMM, 4 block-pipelines per CU ----
// 1032 blocks x 4 waves. Tile = 16 samples x 64 cols. Chunk KC=64:
// A = 4KB (1 contiguous 1KB gl_lds per wave, XOR-source involution),
// B = 8KB (2 contiguous gl_lds per wave). Ring-3 slots (36KB LDS),
// WAITV(6) steady / 3 / 0, raw barriers. Wave w computes col-block 16w.
__launch_bounds__(256, 4)
__global__ void gemm16_kernel(const float* __restrict__ feats,
                              const short* __restrict__ Wbf,
                              const float* __restrict__ breg, const float* __restrict__ bcls,
                              const int* __restrict__ cnt, const int* __restrict__ perm,
                              float* __restrict__ out) {
    __shared__ __align__(16) char lds[3][12288];   // slot: A 4KB @0 | B 8KB @4096
    __shared__ int sRow[16];

    int tid = threadIdx.x, w = tid >> 6, l = tid & 63, lr = l & 15, lq = l >> 4;

    int ts[NG + 1]; ts[0] = 0;
    #pragma unroll
    for (int gg = 0; gg < NG; ++gg) ts[gg + 1] = ts[gg] + ((cnt[gg] + 15) >> 4);
    int b = blockIdx.x;
    if (b >= ts[NG]) return;
    int g = 0;
    #pragma unroll
    for (int gg = 0; gg < NG; ++gg) if (b >= ts[gg + 1]) g = gg + 1;
    int cg = cnt[g];
    int rbase = (b - ts[g]) * 16;
    int nv = cg - rbase; if (nv > 16) nv = 16;

    if (tid < 16) {
        int r = rbase + tid;
        if (r >= cg) r = cg - 1;      // clamp; stores masked by nv
        sRow[tid] = perm[g * NB + r];
    }
    __syncthreads();

    // A staging: lane l stages row 4w+lq, global piece (l&15)^(row&7) -> LDS slot l&15
    int srow = 4 * w + lq;
    const char* aSrc = (const char*)(feats + (size_t)sRow[srow] * ND)
                     + (((l & 15) ^ (srow & 7)) << 4);
    // B staging: wave w stages granules 2w, 2w+1 (contiguous 1KB each)
    const char* bSrc = (const char*)Wbf + (size_t)g * 262144 + (2 * w) * 1024 + l * 16;

    // A read offsets (involution): piece p of row lr lives at slot p^(lr&7)
    const int key = lr & 7;
    const int ra00 = lr * 256 + (((0 * 8 + lq * 2 + 0) ^ key) << 4);
    const int ra01 = lr * 256 + (((0 * 8 + lq * 2 + 1) ^ key) << 4);
    const int ra10 = lr * 256 + (((1 * 8 + lq * 2 + 0) ^ key) << 4);
    const int ra11 = lr * 256 + (((1 * 8 + lq * 2 + 1) ^ key) << 4);
    const int rb0  = 4096 + (2 * w + 0) * 1024 + l * 16;
    const int rb1  = 4096 + (2 * w + 1) * 1024 + l * 16;

#define STAGE(cc, sl) do {                                                     \
        gl_lds16(aSrc + (size_t)(cc) * 256, &lds[sl][w * 1024]);               \
        const char* b_ = bSrc + (size_t)(cc) * 8192;                           \
        gl_lds16(b_,        &lds[sl][4096 + 2 * w * 1024]);                    \
        gl_lds16(b_ + 1024, &lds[sl][4096 + 2 * w * 1024 + 1024]);             \
    } while (0)

    f32x4 acc = {0, 0, 0, 0};

    STAGE(0, 0); STAGE(1, 1);          // 6 outstanding per wave
    int csl = 0;
    #pragma unroll
    for (int c = 0; c < 32; ++c) {
        if (c + 2 < 32) STAGE(c + 2, (c + 2) % 3);   // 9 outstanding
        if (c < 30)       WAITV(6);                  // chunk c landed; 2 in flight
        else if (c == 30) WAITV(3);
        else              WAITV(0);
        BAR();
        {
            const char* s = &lds[csl][0];
            float4 a0 = *(const float4*)(s + ra00);
            float4 a1 = *(const float4*)(s + ra01);
            short8_t af0 = cvt8(a0, a1);
            short8_t b0  = *(const short8_t*)(s + rb0);
            acc = __builtin_amdgcn_mfma_f32_16x16x32_bf16(af0, b0, acc, 0, 0, 0);
            float4 a2 = *(const float4*)(s + ra10);
            float4 a3 = *(const float4*)(s + ra11);
            short8_t af1 = cvt8(a2, a3);
            short8_t b1  = *(const short8_t*)(s + rb1);
            acc = __builtin_amdgcn_mfma_f32_16x16x32_bf16(af1, b1, acc, 0, 0, 0);
        }
        BAR();
        csl = (csl == 2) ? 0 : csl + 1;
    }
#undef STAGE

    // epilogue: bias + scatter to routed rows
    const int B6 = NB * NR;
    int col = w * 16 + lr;
    if (col < NOUT) {
        #pragma unroll
        for (int j = 0; j < 4; ++j) {
            int row = lq * 4 + j;
            if (row < nv) {
                int smp = sRow[row];
                if (col < NR) out[smp * NR + col] = acc[j] + breg[g * NR + col];
                else          out[B6 + smp * NKC + (col - NR)] = acc[j] + bcls[g * NKC + (col - NR)];
            }
        }
    }
}

// ---- tier-3 GEMM (proven R3 path, no blob needed) ----
__launch_bounds__(256, 3)
__global__ void gemm_kernel(const float* __restrict__ feats,
                            const float* __restrict__ Wreg, const float* __restrict__ breg,
                            const float* __restrict__ Wcls, const float* __restrict__ bcls,
                            const int* __restrict__ counts, const int* __restrict__ perm,
                            float* __restrict__ out, int stride) {
    __shared__ __align__(16) short Bsh[2][64][LROW];
    __shared__ int sRow[BM];

    int ts[NG + 1]; ts[0] = 0;
    int off[NG]; int acc = 0;
    #pragma unroll
    for (int gg = 0; gg < NG; ++gg) {
        int c = counts[gg];
        off[gg] = stride ? gg * stride : acc;
        acc += c;
        ts[gg + 1] = ts[gg] + (c + BM - 1) / BM;
    }
    int b = blockIdx.x;
    if (b >= ts[NG]) return;
    int g = 0;
    #pragma unroll
    for (int gg = 0; gg < NG; ++gg) if (b >= ts[gg + 1]) g = gg + 1;
    int gcnt  = counts[g];
    int goff  = off[g];
    int rbase = (b - ts[g]) * BM;
    int nvalid = gcnt - rbase; if (nvalid > BM) nvalid = BM;

    int tid = threadIdx.x;
    if (tid < BM) {
        int r = rbase + tid;
        if (r >= gcnt) r = gcnt - 1;
        sRow[tid] = perm[goff + r];
    }
    __syncthreads();

    int rB = tid >> 2;
    int cq = tid & 3;
    const float* wsrc = nullptr;
    if (rB < NR)        wsrc = Wreg + ((size_t)g * NR + rB) * ND + cq * 32;
    else if (rB < NOUT) wsrc = Wcls + ((size_t)g * NKC + (rB - NR)) * ND + cq * 32;

    int w = tid >> 6, l = tid & 63, lr = l & 15, lq = l >> 4;
    int mt = w & 1, nh = w >> 1;
    const float* aptr = feats + (size_t)sRow[mt * 16 + lr] * ND + lq * 8;
    const short* brp = (const short*)&Bsh[0][0][0] + (nh * 32 + lr) * LROW + lq * 8;

    f32x4 acc0 = {0, 0, 0, 0}, acc1 = {0, 0, 0, 0};
    float4 rb[8];

    if (wsrc) {
        #pragma unroll
        for (int i = 0; i < 8; ++i) rb[i] = *(const float4*)(wsrc + 4 * i);
    } else {
        #pragma unroll
        for (int i = 0; i < 8; ++i) rb[i] = make_float4(0.f, 0.f, 0.f, 0.f);
    }
    {
        short* bw = &Bsh[0][rB][cq * 32];
        #pragma unroll
        for (int j = 0; j < 4; ++j) *(short8_t*)(bw + 8 * j) = cvt8(rb[2 * j], rb[2 * j + 1]);
    }
    __syncthreads();

    #pragma unroll
    for (int c = 0; c < NCH; ++c) {
        const int cur = c & 1, nxt = cur ^ 1;
        if (c + 1 < NCH && wsrc) {
            const float* s = wsrc + (c + 1) * KC;
            #pragma unroll
            for (int i = 0; i < 8; ++i) rb[i] = *(const float4*)(s + 4 * i);
        }
        const short* bp = brp + cur * (64 * LROW);
        const float* ap = aptr + c * KC;
        #pragma unroll
        for (int ks = 0; ks < 4; ++ks) {
            float4 a0 = *(const float4*)(ap + ks * 32);
            float4 a1 = *(const float4*)(ap + ks * 32 + 4);
            short8_t af = cvt8(a0, a1);
            short8_t b0 = *(const short8_t*)(bp + ks * 32);
            short8_t b1 = *(const short8_t*)(bp + 16 * LROW + ks * 32);
            acc0 = __builtin_amdgcn_mfma_f32_16x16x32_bf16(af, b0, acc0, 0, 0, 0);
            acc1 = __builtin_amdgcn_mfma_f32_16x16x32_bf16(af, b1, acc1, 0, 0, 0);
        }
        if (c + 1 < NCH && wsrc) {
            short* bw = &Bsh[nxt][rB][cq * 32];
            #pragma unroll
            for (int j = 0; j < 4; ++j) *(short8_t*)(bw + 8 * j) = cvt8(rb[2 * j], rb[2 * j + 1]);
        } else if (c + 1 < NCH) {
            short8_t z = {0,0,0,0,0,0,0,0};
            short* bw = &Bsh[nxt][rB][cq * 32];
            #pragma unroll
            for (int j = 0; j < 4; ++j) *(short8_t*)(bw + 8 * j) = z;
        }
        __syncthreads();
    }

    const int B6 = NB * NR;
    #pragma unroll
    for (int n = 0; n < 2; ++n) {
        f32x4 v = n ? acc1 : acc0;
        int col = nh * 32 + n * 16 + lr;
        if (col < NOUT) {
            #pragma unroll
            for (int j = 0; j < 4; ++j) {
                int row = mt * 16 + lq * 4 + j;
                if (row < nvalid) {
                    int smp = sRow[row];
                    if (col < NR) out[smp * NR + col] = v[j] + breg[g * NR + col];
                    else          out[B6 + smp * NKC + (col - NR)] = v[j] + bcls[g * NKC + (col - NR)];
                }
            }
        }
    }
}

// ---- tier-4: exact fp32, one wave per sample ----
__global__ void fallback_kernel(const float* __restrict__ feats, const int* __restrict__ roi,
                                const float* __restrict__ Wreg, const float* __restrict__ breg,
                                const float* __restrict__ Wcls, const float* __restrict__ bcls,
                                float* __restrict__ out) {
    int i = blockIdx.x;
    int lane = threadIdx.x;
    int g = roi[i];
    const float* frow = feats + (size_t)i * ND;
    float f[32];
    #pragma unroll
    for (int q = 0; q < 32; ++q) f[q] = frow[lane + 64 * q];
    for (int o = 0; o < NOUT; ++o) {
        const float* wrow = (o < NR) ? Wreg + ((size_t)g * NR + o) * ND
                                     : Wcls + ((size_t)g * NKC + (o - NR)) * ND;
        float p = 0.f;
        #pragma unroll
        for (int q = 0; q < 32; ++q) p += f[q] * wrow[lane + 64 * q];
        #pragma unroll
        for (int s = 32; s; s >>= 1) p += __shfl_xor(p, s);
        if (lane == 0) {
            if (o < NR) out[i * NR + o] = p + breg[g * NR + o];
            else        out[NB * NR + i * NKC + (o - NR)] = p + bcls[g * NKC + (o - NR)];
        }
    }
}

extern "C" void kernel_launch(void* const* d_in, const int* in_sizes, int n_in,
                              void* d_out, int out_size, void* d_ws, size_t ws_size,
                              hipStream_t stream) {
    const float* feats = (const float*)d_in[0];
    const int*   roi   = (const int*)d_in[1];
    const float* Wreg  = (const float*)d_in[2];
    const float* breg  = (const float*)d_in[3];
    const float* Wcls  = (const float*)d_in[4];
    const float* bcls  = (const float*)d_in[5];
    float* out = (float*)d_out;

    const size_t wbfBytes = (size_t)NG * 131072 * 2;              // 2 MB blob
    const size_t need_t1 = wbfBytes + 256 + (size_t)NG * NB * 4;  // blob + fixed-stride perm
    const size_t need_t3 = 256 + (size_t)NB * 4;                  // packed-perm path

    if (ws_size >= need_t1) {
        short* Wbf = (short*)d_ws;
        int* cnt   = (int*)((char*)d_ws + wbfBytes);
        int* perm  = cnt + 64;
        hipMemsetAsync(cnt, 0, 64, stream);
        prep_kernel<<<576, 256, 0, stream>>>(roi, cnt, perm, Wreg, Wcls, Wbf);
        gemm16_kernel<<<NT16, 256, 0, stream>>>(feats, Wbf, breg, bcls, cnt, perm, out);
    } else if (ws_size >= need_t3) {
        int* counts = (int*)d_ws;
        int* ranks  = counts + 8;
        int* perm   = counts + 64;
        hipMemsetAsync(counts, 0, 16 * sizeof(int), stream);
        hist_kernel<<<NB / 256, 256, 0, stream>>>(roi, counts);
        scatter_kernel<<<NB / 256, 256, 0, stream>>>(roi, counts, ranks, perm);
        gemm_kernel<<<MAXT, 256, 0, stream>>>(feats, Wreg, breg, Wcls, bcls, counts, perm, out, 0);
    } else {
        fallback_kernel<<<NB, 64, 0, stream>>>(feats, roi, Wreg, breg, Wcls, bcls, out);
    }
}